// Round 16
// baseline (384.103 us; speedup 1.0000x reference)
//
#include <hip/hip_runtime.h>

typedef __attribute__((ext_vector_type(8))) short bf16x8;   // 8 bf16 = 4 VGPRs
typedef __attribute__((ext_vector_type(4))) float f32x4;    // MFMA C/D

__device__ __forceinline__ float bf2f(unsigned short u){
    unsigned int v = ((unsigned int)u) << 16;
    return __builtin_bit_cast(float, v);
}
__device__ __forceinline__ unsigned short f2bf(float f){
    unsigned int u = __builtin_bit_cast(unsigned int, f);
    u += 0x7FFFu + ((u >> 16) & 1u);   // RTNE (no NaN inputs here)
    return (unsigned short)(u >> 16);
}
// HW packed f32->bf16 RTNE (verified rounds 3/6/8/10/15: absmax identical)
__device__ __forceinline__ unsigned int cvt_pk_bf16(float lo, float hi){
    unsigned int r;
    asm("v_cvt_pk_bf16_f32 %0, %1, %2" : "=v"(r) : "v"(lo), "v"(hi));
    return r;
}
__device__ __forceinline__ unsigned int mulpack(unsigned int u, float xf){
    float flo = __builtin_bit_cast(float, u << 16);
    float fhi = __builtin_bit_cast(float, u & 0xffff0000u);
    return cvt_pk_bf16(xf * flo, xf * fhi);
}

// ---- prep: W (K x 256) fp32 -> Wt (256 x K) bf16, LDS-tiled transpose ----
__global__ void prep_wt(const float* __restrict__ W, unsigned short* __restrict__ Wt, int K){
    __shared__ float tile[64][65];
    const int k0 = blockIdx.x * 64;
    const int j0 = blockIdx.y * 64;
    const int t  = threadIdx.x;              // 256
    #pragma unroll
    for (int it = 0; it < 16; it++){
        int idx = it * 256 + t;
        int kr = idx >> 6, jc = idx & 63;
        tile[kr][jc] = W[(size_t)(k0 + kr) * 256 + j0 + jc];
    }
    __syncthreads();
    #pragma unroll
    for (int it = 0; it < 2; it++){
        int idx = it * 256 + t;
        int jr = idx >> 3, kc = (idx & 7) << 3;
        uint4 tv;
        unsigned short* ts = (unsigned short*)&tv;
        #pragma unroll
        for (int q = 0; q < 8; q++)
            ts[q] = f2bf(tile[kc + q][jr]);
        *(uint4*)(Wt + (size_t)(j0 + jr) * K + k0 + kc) = tv;
    }
}

// ---- prep: x (b,m,d) fp32 -> Xt[b][d][m] bf16 ----
__global__ void prep_x(const float* __restrict__ x, unsigned short* __restrict__ Xt){
    int b = blockIdx.x;
    int t = threadIdx.x;
    #pragma unroll
    for (int it = 0; it < 8; it++){
        int o = it * 256 + t;          // o = d*32 + m
        int d = o >> 5, m = o & 31;
        Xt[(size_t)b * 2048 + o] = f2bf(x[(size_t)b * 2048 + m * 64 + d]);
    }
}

__global__ void init_out(float* __restrict__ out, const float* __restrict__ fcb){
    int i = blockIdx.x * 256 + threadIdx.x;
    if (i < 1024) out[i] = fcb[0];
}

// ---- fused CIN stage: r15 skeleton + BK=64 super-steps + XOR bank swizzle ----
// Per super-step (2 kt): B-reads/MFMA for u=0,1 from Zr; build next 64-k slice
// into Zw; ONE barrier (64 total vs 128). All Zb/Hl accesses swizzled:
// 8-short sub-chunk stored at sub ^ ((row>>3)&7); row stride contributes
// (row&7)*4 banks -> every access class spreads over all 32 banks.
// x transposed (Xlt[m][c]) -> conflict-free build x-read.
// Block: 128 c (2 batch elems), 4 waves, j in [64w, 64w+64).
template<int NN, int LOG2NN, int KTOT, int JX, bool HAS_HOUT>
__global__ __launch_bounds__(256, 2) void cin_stage(
    const unsigned short* __restrict__ Xt,
    const unsigned short* __restrict__ Hin,
    const unsigned short* __restrict__ Wt,
    const float* __restrict__ bias,
    const float* __restrict__ fcW,      // pre-offset for this layer
    unsigned short* __restrict__ Hout,  // [b][d][n] bf16, n in [0,128); null if !HAS_HOUT
    float* __restrict__ out)
{
    constexpr int KT  = KTOT / 32;
    constexpr int KT2 = KTOT / 64;               // super-steps
    constexpr int XTS = 136;                     // Xlt row stride (shorts)
    constexpr int HS  = (NN == 128) ? 136 : 40;  // Hl row stride (shorts)
    constexpr int HM  = (NN == 128) ? 7 : 3;     // Hl sub-swizzle mask
    constexpr int ZSB = 72;                      // Zb row stride (shorts; 144 B)
    constexpr int XTSZ = 32 * XTS;               // 4352 shorts
    constexpr int HLSZ = 128 * HS;
    constexpr int ZBSZ = 128 * ZSB;              // 9216 shorts
    constexpr int NEED = XTSZ + HLSZ + 2 * ZBSZ;
    constexpr int SMSZ = NEED > 17408 ? NEED : 17408;   // Yl overlay: 128*136

    __shared__ unsigned short smem[SMSZ];
    unsigned short* const Xlt = smem;            // [32][136] transposed x
    unsigned short* const Hl  = smem + XTSZ;     // [128][HS] swizzled h (x for NN=32)
    unsigned short* const Zb0 = smem + XTSZ + HLSZ;
    unsigned short* const Zb1 = Zb0 + ZBSZ;
    unsigned short* const Yl  = smem;            // epilogue overlay [n:128][c pad 136]

    const int t    = threadIdx.x;
    const int lane = t & 63;
    const int w    = t >> 6;
    const int li   = lane & 15;
    const int lq   = lane >> 4;
    const int lh   = li >> 3;
    const int bpair = blockIdx.x;

    // ---- one-time staging: x -> Xlt transposed; h -> Hl swizzled ----
    {
        const int c  = t >> 1;                  // 0..127
        const int b  = bpair * 2 + (c >> 6);
        const int d  = c & 63;
        const int half = t & 1;
        const int mh = half << 4;               // 16 shorts (m-range)
        const uint4* xsrc = (const uint4*)(Xt + ((size_t)b << 11) + (d << 5) + mh);
        uint4 x0 = xsrc[0], x1 = xsrc[1];
        const unsigned short* xs0 = (const unsigned short*)&x0;
        const unsigned short* xs1 = (const unsigned short*)&x1;
        #pragma unroll
        for (int q = 0; q < 8; q++) Xlt[(mh + q) * XTS + c]     = xs0[q];
        #pragma unroll
        for (int q = 0; q < 8; q++) Xlt[(mh + 8 + q) * XTS + c] = xs1[q];
        if (NN == 128){
            const uint4* hsrc = (const uint4*)(Hin + (size_t)((b << 6) + d) * 128 + (half << 6));
            #pragma unroll
            for (int q = 0; q < 8; q++){
                uint4 hv = hsrc[q];
                const int sub = ((half << 3) + q) ^ ((c >> 3) & 7);
                *(uint4*)(Hl + c * HS + (sub << 3)) = hv;
            }
        } else {
            const int s0 = ((half << 1) + 0) ^ ((c >> 3) & 3);
            const int s1 = ((half << 1) + 1) ^ ((c >> 3) & 3);
            *(uint4*)(Hl + c * HS + (s0 << 3)) = x0;
            *(uint4*)(Hl + c * HS + (s1 << 3)) = x1;
        }
    }
    __syncthreads();

    // build one 64-k super-slice: thread (zc = t&127, zkh = t>>7) fills
    // 16-short chunks qq in {2*zkh, 2*zkh+1}; all subs swizzled.
    const int zc  = t & 127;
    const int zkh = t >> 7;
    const int zq  = (zc >> 3) & 7;
    auto build = [&](unsigned short* zbuf, int ktp){
        #pragma unroll
        for (int qi = 0; qi < 2; qi++){
            const int qq = (zkh << 1) + qi;              // 0..3
            const int kg = (ktp << 6) + (qq << 4);
            const int m  = kg >> LOG2NN;
            const int n0 = kg & (NN - 1);
            const float xf = bf2f(Xlt[m * XTS + zc]);
            #pragma unroll
            for (int j = 0; j < 2; j++){
                const int hsub = ((n0 >> 3) + j) ^ (zq & HM);
                uint4 hv = *(const uint4*)(Hl + zc * HS + (hsub << 3));
                uint4 zv;
                zv.x = mulpack(hv.x, xf);
                zv.y = mulpack(hv.y, xf);
                zv.z = mulpack(hv.z, xf);
                zv.w = mulpack(hv.w, xf);
                const int zsub = ((qq << 1) + j) ^ zq;
                *(uint4*)(zbuf + zc * ZSB + (zsub << 3)) = zv;
            }
        }
    };

    // A-fragments: lane reads Wt[j = w*64 + jt*16 + li][kt*32 + lq*8 .. +8)
    const unsigned short* wbase = Wt + (size_t)((w << 6) + li) * KTOT + (lq << 3);
    auto loadA = [&](int kt, bf16x8* A){
        const unsigned short* wk = wbase + (kt << 5);
        #pragma unroll
        for (int jt = 0; jt < 4; jt++)
            A[jt] = *(const bf16x8*)(wk + (size_t)jt * 16 * KTOT);
    };

    f32x4 acc[4][8];
    #pragma unroll
    for (int jt = 0; jt < 4; jt++)
        #pragma unroll
        for (int ct = 0; ct < 8; ct++)
            acc[jt][ct] = (f32x4){0.f, 0.f, 0.f, 0.f};

    build(Zb0, 0);
    bf16x8 A0[4], A1[4];
    loadA(0, A0);
    __syncthreads();                 // Zb0(super 0) ready

    for (int ktp = 0; ktp < KT2; ktp++){
        unsigned short* const Zr = (ktp & 1) ? Zb1 : Zb0;
        unsigned short* const Zw = (ktp & 1) ? Zb0 : Zb1;
        const int kt0 = ktp << 1;
        loadA(kt0 + 1, A1);                       // kt0+1 <= KT-1 always
        #pragma unroll
        for (int ct = 0; ct < 8; ct++){
            const int row = (ct << 4) + li;
            const int sub = lq ^ (((ct << 1) + lh) & 7);          // u = 0
            bf16x8 B = *(const bf16x8*)(Zr + row * ZSB + (sub << 3));
            #pragma unroll
            for (int jt = 0; jt < 4; jt++)
                acc[jt][ct] = __builtin_amdgcn_mfma_f32_16x16x32_bf16(A0[jt], B, acc[jt][ct], 0, 0, 0);
        }
        loadA(kt0 + 2 < KT ? kt0 + 2 : KT - 1, A0);
        #pragma unroll
        for (int ct = 0; ct < 8; ct++){
            const int row = (ct << 4) + li;
            const int sub = (4 + lq) ^ (((ct << 1) + lh) & 7);    // u = 1
            bf16x8 B = *(const bf16x8*)(Zr + row * ZSB + (sub << 3));
            #pragma unroll
            for (int jt = 0; jt < 4; jt++)
                acc[jt][ct] = __builtin_amdgcn_mfma_f32_16x16x32_bf16(A1[jt], B, acc[jt][ct], 0, 0, 0);
        }
        if (ktp + 1 < KT2) build(Zw, ktp + 1);    // overlaps in issue stream
        __syncthreads();                          // the only barrier per super-step
    }

    // epilogue: bias + relu; fc partial sums; stage h-half into Yl overlay
    float pfc0 = 0.f, pfc1 = 0.f;
    #pragma unroll
    for (int jt = 0; jt < 4; jt++){
        const int jb = (w << 6) + (jt << 4) + (lq << 2);
        float bv[4], fv[4];
        #pragma unroll
        for (int r = 0; r < 4; r++){
            int j = jb + r;
            bv[r] = bias[j];
            fv[r] = (j < JX) ? fcW[j] : 0.f;
        }
        #pragma unroll
        for (int ct = 0; ct < 8; ct++){
            f32x4 f = acc[jt][ct];
            int c = (ct << 4) + li;
            float ps = 0.f;
            #pragma unroll
            for (int r = 0; r < 4; r++){
                float y = f[r] + bv[r];
                y = y > 0.f ? y : 0.f;
                ps += fv[r] * y;
                if (HAS_HOUT){
                    int j = jb + r;
                    if (j >= 128)
                        Yl[(j - 128) * 136 + c] = f2bf(y);
                }
            }
            if (ct < 4) pfc0 += ps; else pfc1 += ps;
        }
    }
    #pragma unroll
    for (int off = 32; off; off >>= 1){
        pfc0 += __shfl_xor(pfc0, off, 64);
        pfc1 += __shfl_xor(pfc1, off, 64);
    }
    if (lane == 0){
        atomicAdd(out + bpair * 2 + 0, pfc0);
        atomicAdd(out + bpair * 2 + 1, pfc1);
    }

    if (HAS_HOUT){
        __syncthreads();
        // cooperative store: Hout[(bpair*128 + c)*128 + n] = Yl[n][c]
        const int c  = t >> 1;
        const int nh = (t & 1) << 6;
        unsigned short* gdst = Hout + (size_t)(bpair * 128 + c) * 128 + nh;
        #pragma unroll
        for (int i8 = 0; i8 < 8; i8++){
            uint4 tv;
            unsigned short* tmp = (unsigned short*)&tv;
            #pragma unroll
            for (int q = 0; q < 8; q++)
                tmp[q] = Yl[(nh + i8 * 8 + q) * 136 + c];
            *(uint4*)(gdst + i8 * 8) = tv;
        }
    }
}

extern "C" void kernel_launch(void* const* d_in, const int* in_sizes, int n_in,
                              void* d_out, int out_size, void* d_ws, size_t ws_size,
                              hipStream_t stream){
    const float* x   = (const float*)d_in[0];
    const float* W0  = (const float*)d_in[1];
    const float* b0  = (const float*)d_in[2];
    const float* W1  = (const float*)d_in[3];
    const float* b1  = (const float*)d_in[4];
    const float* W2  = (const float*)d_in[5];
    const float* b2  = (const float*)d_in[6];
    const float* fcW = (const float*)d_in[7];
    const float* fcb = (const float*)d_in[8];
    float* out = (float*)d_out;

    char* ws = (char*)d_ws;
    unsigned short* Xt  = (unsigned short*)(ws);             // 4 MB
    unsigned short* Wt0 = (unsigned short*)(ws + 4194304);   // 512 KB
    unsigned short* Wt1 = (unsigned short*)(ws + 4718592);   // 2 MB
    unsigned short* Wt2 = (unsigned short*)(ws + 6815744);   // 2 MB
    unsigned short* H0  = (unsigned short*)(ws + 8912896);   // 16 MB
    unsigned short* H1  = (unsigned short*)(ws + 25690112);  // 16 MB (end 42467328)

    prep_wt<<<dim3(16, 4), 256, 0, stream>>>(W0, Wt0, 1024);
    prep_wt<<<dim3(64, 4), 256, 0, stream>>>(W1, Wt1, 4096);
    prep_wt<<<dim3(64, 4), 256, 0, stream>>>(W2, Wt2, 4096);
    prep_x <<<1024, 256, 0, stream>>>(x, Xt);
    init_out<<<4, 256, 0, stream>>>(out, fcb);

    cin_stage< 32, 5, 1024, 128, true ><<<512, 256, 0, stream>>>(Xt, Xt, Wt0, b0, fcW,       H0, out);
    cin_stage<128, 7, 4096, 128, true ><<<512, 256, 0, stream>>>(Xt, H0, Wt1, b1, fcW + 128, H1, out);
    cin_stage<128, 7, 4096, 256, false><<<512, 256, 0, stream>>>(Xt, H1, Wt2, b2, fcW + 256, nullptr, out);
}